// Round 14
// baseline (586.470 us; speedup 1.0000x reference)
//
#include <hip/hip_runtime.h>
#include <math.h>

#define NN 50000
#define NE 800000
#define NF 512
#define NH 128
#define KF 4
#define NC 64
#define LRELU_ALPHA 0.2f
#define EPSF 1e-16f

typedef unsigned short u16;
typedef __attribute__((ext_vector_type(8))) short bf16x8;
typedef __attribute__((ext_vector_type(4))) float f32x4;

// ---------------- workspace layout (float offsets) ----------------
#define OFF_H      0LL                                  // h (NN,512)
#define OFF_HP     (OFF_H + (long long)NN * NF)         // xhi/xlo (gemm in), then ahi/alo (elu-split planes)
#define OFF_REC    (OFF_HP + (long long)NN * NF)        // rec (NE int4); ALSO Wt split before edge_pre1
#define OFF_XO0    (OFF_REC + 4LL * NE)                 // (NN,64)
#define OFF_SV1    (OFF_XO0 + (long long)NN * NC)       // (NN,8): s_src[4] | s1a[4]
#define OFF_SV2    (OFF_SV1 + (long long)NN * 8)        // (NN,8): s_dst[4] | s2a[4]
#define OFF_WOT    (OFF_SV2 + (long long)NN * 8)        // wohi/wolo (64x512 u16 each)
#define OFF_S1O    (OFF_WOT + (long long)NN * KF)       // (NN,)
#define OFF_S2O    (OFF_S1O + NN)
#define OFF_START  (OFF_S2O + NN)                       // (NN+1) ints, pad
// ---- zeroed-each-call region starts here ----
#define OFF_CNT    (OFF_START + NN + 4)                 // NN ints
#define OFF_CURSOR (OFF_CNT + NN)                       // NN ints
#define OFF_ATT    (OFF_CURSOR + NN)                    // double (2 floats)
#define WS_FLOATS  (OFF_ATT + 2)

__device__ __forceinline__ u16 bf16_rne(float f) {
    unsigned int u = __float_as_uint(f);
    return (u16)((u + 0x7FFFu + ((u >> 16) & 1u)) >> 16);
}
__device__ __forceinline__ float bf16_f(u16 b) {
    return __uint_as_float(((unsigned int)b) << 16);
}

// async global->LDS 16B: dest = wave-uniform base + lane*16 (HW rule)
__device__ __forceinline__ void gload_lds16(const u16* g, u16* l) {
    __builtin_amdgcn_global_load_lds(
        (const __attribute__((address_space(1))) void*)g,
        (__attribute__((address_space(3))) void*)l, 16, 0, 0);
}

// ---------------------------------------------------------------------------
// K0: fused preprocessing. Blocks [0,NSPLIT): split x into hi/lo bf16;
// [NSPLIT, NSPLIT+NCNT): csr_count; rest: W / Wo transpose+split.
#define NSPLIT 12500                 // NN*NF/8/256
#define NCNT   ((NE + 255) / 256)    // 3125
__global__ __launch_bounds__(256) void split_all(
        const float* __restrict__ x, u16* __restrict__ xhi, u16* __restrict__ xlo,
        const int* __restrict__ edge, int* __restrict__ cnt,
        const float* __restrict__ Wks, const float* __restrict__ Wo,
        u16* __restrict__ wthi, u16* __restrict__ wtlo,
        u16* __restrict__ wohi, u16* __restrict__ wolo) {
    if (blockIdx.x < NSPLIT) {
        size_t i = ((size_t)blockIdx.x * 256 + threadIdx.x) * 8;
        float4 v0 = *(const float4*)(x + i);
        float4 v1 = *(const float4*)(x + i + 4);
        float v[8] = {v0.x, v0.y, v0.z, v0.w, v1.x, v1.y, v1.z, v1.w};
        unsigned int hp[4], lp[4];
#pragma unroll
        for (int j = 0; j < 4; ++j) {
            u16 h0 = bf16_rne(v[2 * j]);
            u16 h1 = bf16_rne(v[2 * j + 1]);
            u16 l0 = bf16_rne(v[2 * j] - bf16_f(h0));
            u16 l1 = bf16_rne(v[2 * j + 1] - bf16_f(h1));
            hp[j] = (unsigned int)h0 | ((unsigned int)h1 << 16);
            lp[j] = (unsigned int)l0 | ((unsigned int)l1 << 16);
        }
        *(uint4*)(xhi + i) = make_uint4(hp[0], hp[1], hp[2], hp[3]);
        *(uint4*)(xlo + i) = make_uint4(lp[0], lp[1], lp[2], lp[3]);
    } else if (blockIdx.x < NSPLIT + NCNT) {
        int e = (blockIdx.x - NSPLIT) * 256 + threadIdx.x;
        if (e < NE) atomicAdd(&cnt[edge[e]], 1);
    } else {
        int b = blockIdx.x - NSPLIT - NCNT;   // 0..575
        if (b < 512) {
            int kf = b >> 7, n = b & 127;
            for (int f = threadIdx.x; f < NF; f += 256) {
                float v = Wks[(size_t)kf * (NF * NH) + (size_t)f * NH + n];
                u16 hb = bf16_rne(v);
                u16 lb = bf16_rne(v - bf16_f(hb));
                wthi[(size_t)b * NF + f] = hb;
                wtlo[(size_t)b * NF + f] = lb;
            }
        } else {
            int n = b - 512;   // 0..63
            for (int f = threadIdx.x; f < NF; f += 256) {
                float v = Wo[(size_t)f * NC + n];
                u16 hb = bf16_rne(v);
                u16 lb = bf16_rne(v - bf16_f(hb));
                wohi[(size_t)n * NF + f] = hb;
                wolo[(size_t)n * NF + f] = lb;
            }
        }
    }
}

// ---------------------------------------------------------------------------
// K1: h = x @ Wcat via 3-term split-bf16 MFMA, gload_lds staging, XCD-chunked
// bijective block swizzle.
__global__ __launch_bounds__(256) void gemm_h_mfma(
        const u16* __restrict__ xhi, const u16* __restrict__ xlo,
        const u16* __restrict__ wthi, const u16* __restrict__ wtlo,
        float* __restrict__ h) {
    __shared__ u16 Ah[128 * 32], Al[128 * 32], Bh[128 * 32], Bl[128 * 32];
    const int nwg = 4 * ((NN + 127) / 128);
    const int q = nwg / 8, r = nwg % 8;
    int o = blockIdx.x;
    int xcd = o & 7, pos = o >> 3;
    int wg = (xcd < r ? xcd * (q + 1) : r * (q + 1) + (xcd - r) * q) + pos;
    int m0 = (wg >> 2) * 128, n0 = (wg & 3) * 128;

    int tid = threadIdx.x;
    int lane = tid & 63;
    int wave = tid >> 6, wm = wave >> 1, wn = wave & 1;
    f32x4 acc[4][4];
#pragma unroll
    for (int i = 0; i < 4; ++i)
#pragma unroll
        for (int j = 0; j < 4; ++j) acc[i][j] = (f32x4)(0.f);

    u16* sbuf = (wave == 0) ? Ah : (wave == 1) ? Al : (wave == 2) ? Bh : Bl;
    const u16* gbase = (wave == 0) ? xhi : (wave == 1) ? xlo
                     : (wave == 2) ? wthi : wtlo;
    int rowbase = (wave < 2) ? m0 : n0;
    int c16s = (lane & 3) ^ ((lane >> 2) & 3) ^ (lane >> 4);
    const u16* gsrc[8];
#pragma unroll
    for (int i = 0; i < 8; ++i) {
        int rowg = rowbase + 16 * i + (lane >> 2);
        if (wave < 2 && rowg >= NN) rowg = NN - 1;
        gsrc[i] = gbase + (size_t)rowg * NF + c16s * 8;
    }

    const int arow = wm * 64 + (lane & 15);
    const int brow = wn * 64 + (lane & 15);
    const int rc16 = (lane >> 4) ^ ((lane & 3) ^ ((lane >> 2) & 3));
    const int fragoff = rc16 * 8;

    for (int k0 = 0; k0 < NF; k0 += 32) {
        __syncthreads();
#pragma unroll
        for (int i = 0; i < 8; ++i)
            gload_lds16(gsrc[i] + k0, sbuf + i * 512);
        __syncthreads();
        bf16x8 ah[4], al[4], bh[4], bl[4];
#pragma unroll
        for (int mi = 0; mi < 4; ++mi) {
            ah[mi] = *(const bf16x8*)(Ah + (arow + mi * 16) * 32 + fragoff);
            al[mi] = *(const bf16x8*)(Al + (arow + mi * 16) * 32 + fragoff);
        }
#pragma unroll
        for (int ni = 0; ni < 4; ++ni) {
            bh[ni] = *(const bf16x8*)(Bh + (brow + ni * 16) * 32 + fragoff);
            bl[ni] = *(const bf16x8*)(Bl + (brow + ni * 16) * 32 + fragoff);
        }
#pragma unroll
        for (int mi = 0; mi < 4; ++mi)
#pragma unroll
            for (int ni = 0; ni < 4; ++ni) {
                acc[mi][ni] = __builtin_amdgcn_mfma_f32_16x16x32_bf16(
                    ah[mi], bh[ni], acc[mi][ni], 0, 0, 0);
                acc[mi][ni] = __builtin_amdgcn_mfma_f32_16x16x32_bf16(
                    ah[mi], bl[ni], acc[mi][ni], 0, 0, 0);
                acc[mi][ni] = __builtin_amdgcn_mfma_f32_16x16x32_bf16(
                    al[mi], bh[ni], acc[mi][ni], 0, 0, 0);
            }
    }
#pragma unroll
    for (int mi = 0; mi < 4; ++mi) {
        int mbase = m0 + wm * 64 + mi * 16 + (lane >> 4) * 4;
#pragma unroll
        for (int ni = 0; ni < 4; ++ni) {
            int n = n0 + wn * 64 + ni * 16 + (lane & 15);
#pragma unroll
            for (int r2 = 0; r2 < 4; ++r2) {
                int m = mbase + r2;
                if (m < NN) h[(size_t)m * NF + n] = acc[mi][ni][r2];
            }
        }
    }
}

// ---------------------------------------------------------------------------
// K2: routing/attention scalars from h, packed per node. 2048 blocks so each
// SIMD carries ~8 waves (R12's 256-block version had 1 wave/SIMD -> latency-
// starved).
__global__ __launch_bounds__(256) void compute_svals_h(
        const float* __restrict__ h, const float* __restrict__ a_k,
        const float* __restrict__ a_att,
        float* __restrict__ sv1, float* __restrict__ sv2) {
    __shared__ float Ak[4][1024];
    __shared__ float Aa[4][256];
    for (int i = threadIdx.x; i < 4096; i += 256) Ak[i >> 10][i & 1023] = a_k[i];
    for (int i = threadIdx.x; i < 1024; i += 256) Aa[i >> 8][i & 255] = a_att[i];
    __syncthreads();
    int w = threadIdx.x >> 6, lane = threadIdx.x & 63;
    for (int n = blockIdx.x * 4 + w; n < NN; n += gridDim.x * 4) {
        const float* hr = h + (size_t)n * NF;
        float accS[4] = {0, 0, 0, 0}, accD[4] = {0, 0, 0, 0};
        float accQ1[4] = {0, 0, 0, 0}, accQ2[4] = {0, 0, 0, 0};
#pragma unroll
        for (int i = 0; i < 8; ++i) {
            int f = i * 64 + lane;
            float hv = hr[f];
#pragma unroll
            for (int k = 0; k < 4; ++k) {
                accS[k] = fmaf(hv, Ak[k][f], accS[k]);
                accD[k] = fmaf(hv, Ak[k][512 + f], accD[k]);
            }
            accQ1[i >> 1] = fmaf(hv, Aa[i >> 1][f & 127], accQ1[i >> 1]);
            accQ2[i >> 1] = fmaf(hv, Aa[i >> 1][128 + (f & 127)], accQ2[i >> 1]);
        }
#pragma unroll
        for (int off = 32; off >= 1; off >>= 1) {
#pragma unroll
            for (int k = 0; k < 4; ++k) {
                accS[k] += __shfl_xor(accS[k], off);
                accD[k] += __shfl_xor(accD[k], off);
                accQ1[k] += __shfl_xor(accQ1[k], off);
                accQ2[k] += __shfl_xor(accQ2[k], off);
            }
        }
        if (lane == 0) {
#pragma unroll
            for (int k = 0; k < 4; ++k) {
                sv1[(size_t)n * 8 + k]     = accS[k];
                sv1[(size_t)n * 8 + 4 + k] = accQ1[k];
                sv2[(size_t)n * 8 + k]     = accD[k];
                sv2[(size_t)n * 8 + 4 + k] = accQ2[k];
            }
        }
    }
}

// ---------------------------------------------------------------------------
__global__ __launch_bounds__(1024) void csr_scan(const int* __restrict__ cnt,
                                                 int* __restrict__ start) {
    __shared__ int part[1024];
    int t = threadIdx.x;
    const int CH = (NN + 1023) / 1024;  // 49
    int base = t * CH;
    int s = 0;
    for (int i = 0; i < CH; ++i) {
        int idx = base + i;
        if (idx < NN) s += cnt[idx];
    }
    part[t] = s;
    __syncthreads();
    for (int off = 1; off < 1024; off <<= 1) {
        int v = (t >= off) ? part[t - off] : 0;
        __syncthreads();
        part[t] += v;
        __syncthreads();
    }
    int run = (t == 0) ? 0 : part[t - 1];
    for (int i = 0; i < CH; ++i) {
        int idx = base + i;
        if (idx < NN) { start[idx] = run; run += cnt[idx]; }
    }
    if (t == 1023) start[NN] = run;
}

// ---------------------------------------------------------------------------
// K3: edge-parallel scalar precompute + CSR fill. One thread per edge.
__global__ __launch_bounds__(256) void edge_pre1(
        const int* __restrict__ edge, const int* __restrict__ start,
        int* __restrict__ cursor,
        const float* __restrict__ sv1, const float* __restrict__ sv2,
        int4* __restrict__ rec, double* __restrict__ att_acc) {
    __shared__ float blk[4];
    int tid = threadIdx.x;
    int e = blockIdx.x * 256 + tid;
    float t2 = 0.f;
    if (e < NE) {
        int src = edge[e];
        int dst = edge[NE + e];
        const float* p1 = sv1 + (size_t)src * 8;
        const float* p2 = sv2 + (size_t)dst * 8;
        float4 ss = *(const float4*)(p1);
        float4 q1 = *(const float4*)(p1 + 4);
        float4 sd = *(const float4*)(p2);
        float4 q2 = *(const float4*)(p2 + 4);
        float l0 = ss.x + sd.x, l1 = ss.y + sd.y, l2 = ss.z + sd.z, l3 = ss.w + sd.w;
        int i1 = 0; float v1 = l0;
        if (l1 > v1) { v1 = l1; i1 = 1; }
        if (l2 > v1) { v1 = l2; i1 = 2; }
        if (l3 > v1) { v1 = l3; i1 = 3; }
        int i2 = 0; float v2 = -3.4e38f;
        if (i1 != 0)            { v2 = l0; i2 = 0; }
        if (i1 != 1 && l1 > v2) { v2 = l1; i2 = 1; }
        if (i1 != 2 && l2 > v2) { v2 = l2; i2 = 2; }
        if (i1 != 3 && l3 > v2) { v2 = l3; i2 = 3; }
        float esum = expf(l0 - v1) + expf(l1 - v1) + expf(l2 - v1) + expf(l3 - v1);
        t2 = (1.f + expf(v2 - v1)) / esum;
        float q1v1 = i1 == 0 ? q1.x : i1 == 1 ? q1.y : i1 == 2 ? q1.z : q1.w;
        float q2v1 = i1 == 0 ? q2.x : i1 == 1 ? q2.y : i1 == 2 ? q2.z : q2.w;
        float q1v2 = i2 == 0 ? q1.x : i2 == 1 ? q1.y : i2 == 2 ? q1.z : q1.w;
        float q2v2 = i2 == 0 ? q2.x : i2 == 1 ? q2.y : i2 == 2 ? q2.z : q2.w;
        float sv1v = q1v1 + q2v1, sv2v = q1v2 + q2v2;
        float ee1 = expf(-(sv1v >= 0.f ? sv1v : LRELU_ALPHA * sv1v));
        float ee2 = expf(-(sv2v >= 0.f ? sv2v : LRELU_ALPHA * sv2v));
        int p = start[src] + atomicAdd(&cursor[src], 1);
        rec[p] = make_int4(dst, src | (i1 << 16) | (i2 << 18),
                           __float_as_int(ee1), __float_as_int(ee2));
    }
#pragma unroll
    for (int off = 32; off >= 1; off >>= 1) t2 += __shfl_xor(t2, off);
    if ((tid & 63) == 0) blk[tid >> 6] = t2;
    __syncthreads();
    if (tid == 0)
        atomicAdd(att_acc, (double)(blk[0] + blk[1] + blk[2] + blk[3]));
}

// ---------------------------------------------------------------------------
// K4: layer-1 gather, unrolled x4 (load-phase / accumulate-phase split so up
// to 4 rec + 16 row loads are in flight). Per-wave accumulation order is by
// increasing j, identical to the rolled loop -> bit-identical results.
#define G1_LOAD(RR, T)                                                          \
    int i1##T = __builtin_amdgcn_readfirstlane(((RR).y >> 16) & 3);             \
    int i2##T = __builtin_amdgcn_readfirstlane(((RR).y >> 18) & 3);             \
    int dd##T = __builtin_amdgcn_readfirstlane((RR).x);                         \
    float w1##T = __uint_as_float(__builtin_amdgcn_readfirstlane((RR).z));      \
    float w2##T = __uint_as_float(__builtin_amdgcn_readfirstlane((RR).w));      \
    const float* hr##T = h + (size_t)dd##T * NF + lane;                         \
    float v1a##T = hr##T[i1##T * 128];                                          \
    float v1b##T = hr##T[i1##T * 128 + 64];                                     \
    float v2a##T = hr##T[i2##T * 128];                                          \
    float v2b##T = hr##T[i2##T * 128 + 64];

#define G1_ACC(T)                                                               \
    switch (i1##T) {                                                            \
        case 0: a00 = fmaf(w1##T, v1a##T, a00); a01 = fmaf(w1##T, v1b##T, a01); rs0 += w1##T; break; \
        case 1: a10 = fmaf(w1##T, v1a##T, a10); a11 = fmaf(w1##T, v1b##T, a11); rs1 += w1##T; break; \
        case 2: a20 = fmaf(w1##T, v1a##T, a20); a21 = fmaf(w1##T, v1b##T, a21); rs2 += w1##T; break; \
        default:a30 = fmaf(w1##T, v1a##T, a30); a31 = fmaf(w1##T, v1b##T, a31); rs3 += w1##T; break; \
    }                                                                           \
    switch (i2##T) {                                                            \
        case 0: a00 = fmaf(w2##T, v2a##T, a00); a01 = fmaf(w2##T, v2b##T, a01); rs0 += w2##T; break; \
        case 1: a10 = fmaf(w2##T, v2a##T, a10); a11 = fmaf(w2##T, v2b##T, a11); rs1 += w2##T; break; \
        case 2: a20 = fmaf(w2##T, v2a##T, a20); a21 = fmaf(w2##T, v2b##T, a21); rs2 += w2##T; break; \
        default:a30 = fmaf(w2##T, v2a##T, a30); a31 = fmaf(w2##T, v2b##T, a31); rs3 += w2##T; break; \
    }

__global__ __launch_bounds__(256) void node_gather1(
        const int* __restrict__ start, const int4* __restrict__ rec,
        const float* __restrict__ h,
        u16* __restrict__ ahi, u16* __restrict__ alo) {
    __shared__ float red[4][512];
    __shared__ float rsred[4][4];
    int n = blockIdx.x;
    int w = threadIdx.x >> 6, lane = threadIdx.x & 63;
    int j0 = __builtin_amdgcn_readfirstlane(start[n]);
    int j1 = __builtin_amdgcn_readfirstlane(start[n + 1]);
    float a00 = 0.f, a01 = 0.f, a10 = 0.f, a11 = 0.f;
    float a20 = 0.f, a21 = 0.f, a30 = 0.f, a31 = 0.f;
    float rs0 = 0.f, rs1 = 0.f, rs2 = 0.f, rs3 = 0.f;
    int j = j0 + w;
    for (; j + 12 < j1; j += 16) {      // 4 records in flight
        int4 r0 = rec[j];
        int4 r1 = rec[j + 4];
        int4 r2 = rec[j + 8];
        int4 r3 = rec[j + 12];
        G1_LOAD(r0, A) G1_LOAD(r1, B) G1_LOAD(r2, C) G1_LOAD(r3, D)
        G1_ACC(A) G1_ACC(B) G1_ACC(C) G1_ACC(D)
    }
    for (; j < j1; j += 4) {
        int4 r0 = rec[j];
        G1_LOAD(r0, A)
        G1_ACC(A)
    }
    red[w][lane]       = a00; red[w][64 + lane]  = a01;
    red[w][128 + lane] = a10; red[w][192 + lane] = a11;
    red[w][256 + lane] = a20; red[w][320 + lane] = a21;
    red[w][384 + lane] = a30; red[w][448 + lane] = a31;
    if (lane == 0) {
        rsred[w][0] = rs0; rsred[w][1] = rs1; rsred[w][2] = rs2; rsred[w][3] = rs3;
    }
    __syncthreads();
    int t = threadIdx.x;
    float s0 = (red[0][t] + red[1][t]) + (red[2][t] + red[3][t]);
    float s1 = (red[0][256 + t] + red[1][256 + t]) + (red[2][256 + t] + red[3][256 + t]);
    int f0 = t >> 7, f1 = 2 + (t >> 7);
    float rsa = (rsred[0][f0] + rsred[1][f0]) + (rsred[2][f0] + rsred[3][f0]) + EPSF;
    float rsb = (rsred[0][f1] + rsred[1][f1]) + (rsred[2][f1] + rsred[3][f1]) + EPSF;
    float e0 = s0 / rsa; e0 = e0 > 0.f ? e0 : expm1f(e0);
    float e1 = s1 / rsb; e1 = e1 > 0.f ? e1 : expm1f(e1);
    u16 h0 = bf16_rne(e0), l0 = bf16_rne(e0 - bf16_f(h0));
    u16 h1 = bf16_rne(e1), l1 = bf16_rne(e1 - bf16_f(h1));
    u16* ah = ahi + (size_t)n * NF;
    u16* al = alo + (size_t)n * NF;
    ah[t] = h0; ah[256 + t] = h1;
    al[t] = l0; al[256 + t] = l1;
}

// ---------------------------------------------------------------------------
// K5: xo0 = elu_cat @ W_o via 3-term split-bf16 MFMA + fused s1o/s2o dots.
__global__ __launch_bounds__(256) void node_pass_mfma(
        const u16* __restrict__ ahi, const u16* __restrict__ alo,
        const u16* __restrict__ wohi, const u16* __restrict__ wolo,
        const float* __restrict__ a_out,
        float* __restrict__ xo0, float* __restrict__ s1o, float* __restrict__ s2o) {
    __shared__ u16 Ah[128 * 32], Al[128 * 32], Bh[64 * 32], Bl[64 * 32];
    __shared__ float part1[2][64][2];
    __shared__ float part2[2][64][2];
    int m0 = blockIdx.x * 128;
    int tid = threadIdx.x;
    int lane = tid & 63;
    int wave = tid >> 6, wm = wave >> 1, wn = wave & 1;
    f32x4 acc[4][2];
#pragma unroll
    for (int i = 0; i < 4; ++i)
#pragma unroll
        for (int j = 0; j < 2; ++j) acc[i][j] = (f32x4)(0.f);

    u16* sbuf = (wave == 0) ? Ah : (wave == 1) ? Al : (wave == 2) ? Bh : Bl;
    const u16* gbase = (wave == 0) ? ahi : (wave == 1) ? alo
                     : (wave == 2) ? wohi : wolo;
    int nld = (wave < 2) ? 8 : 4;
    int c16s = (lane & 3) ^ ((lane >> 2) & 3) ^ (lane >> 4);
    const u16* gsrc[8];
#pragma unroll
    for (int i = 0; i < 8; ++i) {
        int rowg = ((wave < 2) ? m0 : 0) + 16 * i + (lane >> 2);
        if (wave < 2 && rowg >= NN) rowg = NN - 1;
        gsrc[i] = gbase + (size_t)rowg * NF + c16s * 8;
    }

    const int arow = wm * 64 + (lane & 15);
    const int brow = wn * 32 + (lane & 15);
    const int rc16 = (lane >> 4) ^ ((lane & 3) ^ ((lane >> 2) & 3));
    const int fragoff = rc16 * 8;

    for (int k0 = 0; k0 < NF; k0 += 32) {
        __syncthreads();
        for (int i = 0; i < nld; ++i)
            gload_lds16(gsrc[i] + k0, sbuf + i * 512);
        __syncthreads();
        bf16x8 ah[4], al[4], bh[2], bl[2];
#pragma unroll
        for (int mi = 0; mi < 4; ++mi) {
            ah[mi] = *(const bf16x8*)(Ah + (arow + mi * 16) * 32 + fragoff);
            al[mi] = *(const bf16x8*)(Al + (arow + mi * 16) * 32 + fragoff);
        }
#pragma unroll
        for (int ni = 0; ni < 2; ++ni) {
            bh[ni] = *(const bf16x8*)(Bh + (brow + ni * 16) * 32 + fragoff);
            bl[ni] = *(const bf16x8*)(Bl + (brow + ni * 16) * 32 + fragoff);
        }
#pragma unroll
        for (int mi = 0; mi < 4; ++mi)
#pragma unroll
            for (int ni = 0; ni < 2; ++ni) {
                acc[mi][ni] = __builtin_amdgcn_mfma_f32_16x16x32_bf16(
                    ah[mi], bh[ni], acc[mi][ni], 0, 0, 0);
                acc[mi][ni] = __builtin_amdgcn_mfma_f32_16x16x32_bf16(
                    ah[mi], bl[ni], acc[mi][ni], 0, 0, 0);
                acc[mi][ni] = __builtin_amdgcn_mfma_f32_16x16x32_bf16(
                    al[mi], bh[ni], acc[mi][ni], 0, 0, 0);
            }
    }
    // xo0 store
#pragma unroll
    for (int mi = 0; mi < 4; ++mi) {
        int mbase = m0 + wm * 64 + mi * 16 + (lane >> 4) * 4;
#pragma unroll
        for (int ni = 0; ni < 2; ++ni) {
            int n = wn * 32 + ni * 16 + (lane & 15);
#pragma unroll
            for (int r2 = 0; r2 < 4; ++r2) {
                int m = mbase + r2;
                if (m < NN) xo0[(size_t)m * NC + n] = acc[mi][ni][r2];
            }
        }
    }
    // fused dots
    float ao1[2], ao2[2];
#pragma unroll
    for (int ni = 0; ni < 2; ++ni) {
        int c = wn * 32 + ni * 16 + (lane & 15);
        ao1[ni] = a_out[c];
        ao2[ni] = a_out[64 + c];
    }
#pragma unroll
    for (int mi = 0; mi < 4; ++mi)
#pragma unroll
        for (int r2 = 0; r2 < 4; ++r2) {
            float p1 = acc[mi][0][r2] * ao1[0] + acc[mi][1][r2] * ao1[1];
            float p2 = acc[mi][0][r2] * ao2[0] + acc[mi][1][r2] * ao2[1];
#pragma unroll
            for (int off = 8; off >= 1; off >>= 1) {
                p1 += __shfl_xor(p1, off);
                p2 += __shfl_xor(p2, off);
            }
            if ((lane & 15) == 0) {
                int rl = mi * 16 + (lane >> 4) * 4 + r2;
                part1[wm][rl][wn] = p1;
                part2[wm][rl][wn] = p2;
            }
        }
    __syncthreads();
    if (tid < 128) {
        int m = m0 + tid;
        if (m < NN) {
            s1o[m] = part1[tid >> 6][tid & 63][0] + part1[tid >> 6][tid & 63][1];
            s2o[m] = part2[tid >> 6][tid & 63][0] + part2[tid >> 6][tid & 63][1];
        }
    }
}

// ---------------------------------------------------------------------------
// K6: output attention gather, unrolled x4 (4 dependent chains in flight),
// fused elu + log-softmax; block 0 finalizes att_loss. Accumulation order per
// wave unchanged -> bit-identical.
__global__ __launch_bounds__(256) void node_gather2(
        const int* __restrict__ start, const int4* __restrict__ rec,
        const float* __restrict__ s1o, const float* __restrict__ s2o,
        const float* __restrict__ xo0, const double* __restrict__ att_acc,
        float* __restrict__ out) {
    __shared__ float red[4][64];
    __shared__ float rsl[4];
    if (blockIdx.x == 0 && threadIdx.x == 0)
        out[(size_t)NN * NC] = 1.f - (float)(att_acc[0] / (double)NE);
    int n = blockIdx.x;
    int w = threadIdx.x >> 6, lane = threadIdx.x & 63;
    int j0 = __builtin_amdgcn_readfirstlane(start[n]);
    int j1 = __builtin_amdgcn_readfirstlane(start[n + 1]);
    float s1n = s1o[n];
    float acc = 0.f, rsum = 0.f;
    int j = j0 + w;
    for (; j + 12 < j1; j += 16) {
        int d0 = __builtin_amdgcn_readfirstlane(rec[j].x);
        int d1 = __builtin_amdgcn_readfirstlane(rec[j + 4].x);
        int d2 = __builtin_amdgcn_readfirstlane(rec[j + 8].x);
        int d3 = __builtin_amdgcn_readfirstlane(rec[j + 12].x);
        float t0 = s1n + s2o[d0];
        float t1 = s1n + s2o[d1];
        float t2 = s1n + s2o[d2];
        float t3 = s1n + s2o[d3];
        float x0 = xo0[(size_t)d0 * NC + lane];
        float x1 = xo0[(size_t)d1 * NC + lane];
        float x2 = xo0[(size_t)d2 * NC + lane];
        float x3 = xo0[(size_t)d3 * NC + lane];
        float e0 = expf(-(t0 >= 0.f ? t0 : LRELU_ALPHA * t0));
        float e1 = expf(-(t1 >= 0.f ? t1 : LRELU_ALPHA * t1));
        float e2 = expf(-(t2 >= 0.f ? t2 : LRELU_ALPHA * t2));
        float e3 = expf(-(t3 >= 0.f ? t3 : LRELU_ALPHA * t3));
        acc = fmaf(e0, x0, acc); rsum += e0;
        acc = fmaf(e1, x1, acc); rsum += e1;
        acc = fmaf(e2, x2, acc); rsum += e2;
        acc = fmaf(e3, x3, acc); rsum += e3;
    }
    for (; j < j1; j += 4) {
        int d = __builtin_amdgcn_readfirstlane(rec[j].x);
        float sv = s1n + s2o[d];
        float e = expf(-(sv >= 0.f ? sv : LRELU_ALPHA * sv));
        acc = fmaf(e, xo0[(size_t)d * NC + lane], acc);
        rsum += e;
    }
    red[w][lane] = acc;
    if (lane == 0) rsl[w] = rsum;
    __syncthreads();
    if (w == 0) {
        float a = (red[0][lane] + red[1][lane]) + (red[2][lane] + red[3][lane]);
        float r = (rsl[0] + rsl[1]) + (rsl[2] + rsl[3]);
        float t = a / (r + EPSF);
        float v = t > 0.f ? t : expm1f(t);
        float m = v;
#pragma unroll
        for (int off = 32; off >= 1; off >>= 1) m = fmaxf(m, __shfl_xor(m, off));
        float p = expf(v - m);
#pragma unroll
        for (int off = 32; off >= 1; off >>= 1) p += __shfl_xor(p, off);
        out[(size_t)n * NC + lane] = v - m - logf(p);
    }
}

// ---------------------------------------------------------------------------
extern "C" void kernel_launch(void* const* d_in, const int* in_sizes, int n_in,
                              void* d_out, int out_size, void* d_ws, size_t ws_size,
                              hipStream_t stream) {
    const float* x     = (const float*)d_in[0];
    const int*   edge  = (const int*)d_in[1];
    const float* Wks   = (const float*)d_in[2];
    const float* a_k   = (const float*)d_in[3];
    const float* Wo    = (const float*)d_in[4];
    const float* a_att = (const float*)d_in[5];
    const float* a_out = (const float*)d_in[6];
    float* out = (float*)d_out;

    float* wsf = (float*)d_ws;
    float* h      = wsf + OFF_H;
    int4*  rec    = (int4*)(wsf + OFF_REC);
    float* xo0    = wsf + OFF_XO0;
    float* sv1    = wsf + OFF_SV1;
    float* sv2    = wsf + OFF_SV2;
    float* s1o    = wsf + OFF_S1O;
    float* s2o    = wsf + OFF_S2O;
    int*   startp = (int*)(wsf + OFF_START);
    int*   cnt    = (int*)(wsf + OFF_CNT);
    int*   cursor = (int*)(wsf + OFF_CURSOR);
    double* att   = (double*)(wsf + OFF_ATT);

    u16* xhi  = (u16*)(wsf + OFF_HP);
    u16* xlo  = xhi + (size_t)NN * NF;
    u16* ahi  = xhi;
    u16* alo  = xlo;
    u16* wthi = (u16*)(wsf + OFF_REC);
    u16* wtlo = wthi + (size_t)KF * NH * NF;
    u16* wohi = (u16*)(wsf + OFF_WOT);
    u16* wolo = wohi + (size_t)NC * NF;

    size_t zero_bytes = (size_t)(WS_FLOATS - OFF_CNT) * sizeof(float);
    hipMemsetAsync((char*)d_ws + (size_t)OFF_CNT * sizeof(float), 0, zero_bytes, stream);

    split_all<<<NSPLIT + NCNT + 576, 256, 0, stream>>>(
        x, xhi, xlo, edge, cnt, Wks, Wo, wthi, wtlo, wohi, wolo);
    csr_scan<<<1, 1024, 0, stream>>>(cnt, startp);
    gemm_h_mfma<<<4 * ((NN + 127) / 128), 256, 0, stream>>>(xhi, xlo, wthi, wtlo, h);
    compute_svals_h<<<2048, 256, 0, stream>>>(h, a_k, a_att, sv1, sv2);
    edge_pre1<<<(NE + 255) / 256, 256, 0, stream>>>(edge, startp, cursor,
                                                    sv1, sv2, rec, att);
    node_gather1<<<NN, 256, 0, stream>>>(startp, rec, h, ahi, alo);
    node_pass_mfma<<<(NN + 127) / 128, 256, 0, stream>>>(ahi, alo, wohi, wolo,
                                                         a_out, xo0, s1o, s2o);
    node_gather2<<<NN, 256, 0, stream>>>(startp, rec, s1o, s2o, xo0, att, out);
}

// Round 15
// 586.340 us; speedup vs baseline: 1.0002x; 1.0002x over previous
//
#include <hip/hip_runtime.h>
#include <math.h>

#define NN 50000
#define NE 800000
#define NF 512
#define NH 128
#define KF 4
#define NC 64
#define LRELU_ALPHA 0.2f
#define EPSF 1e-16f

typedef unsigned short u16;
typedef __attribute__((ext_vector_type(8))) short bf16x8;
typedef __attribute__((ext_vector_type(4))) float f32x4;

// ---------------- workspace layout (float offsets) ----------------
#define OFF_H      0LL                                  // h (NN,512)
#define OFF_HP     (OFF_H + (long long)NN * NF)         // xhi/xlo (gemm in), then ahi/alo (elu-split planes)
#define OFF_REC    (OFF_HP + (long long)NN * NF)        // rec (NE int4); ALSO Wt split before edge_pre1
#define OFF_XO0    (OFF_REC + 4LL * NE)                 // (NN,64)
#define OFF_SV1    (OFF_XO0 + (long long)NN * NC)       // (NN,8): s_src[4] | s1a[4]
#define OFF_SV2    (OFF_SV1 + (long long)NN * 8)        // (NN,8): s_dst[4] | s2a[4]
#define OFF_WOT    (OFF_SV2 + (long long)NN * 8)        // wohi/wolo (64x512 u16 each)
#define OFF_S1O    (OFF_WOT + (long long)NN * KF)       // (NN,)
#define OFF_S2O    (OFF_S1O + NN)
#define OFF_START  (OFF_S2O + NN)                       // (NN+1) ints, pad
// ---- zeroed-each-call region starts here ----
#define OFF_CNT    (OFF_START + NN + 4)                 // NN ints
#define OFF_CURSOR (OFF_CNT + NN)                       // NN ints
#define OFF_ATT    (OFF_CURSOR + NN)                    // double (2 floats)
#define WS_FLOATS  (OFF_ATT + 2)

__device__ __forceinline__ u16 bf16_rne(float f) {
    unsigned int u = __float_as_uint(f);
    return (u16)((u + 0x7FFFu + ((u >> 16) & 1u)) >> 16);
}
__device__ __forceinline__ float bf16_f(u16 b) {
    return __uint_as_float(((unsigned int)b) << 16);
}

// async global->LDS 16B: dest = wave-uniform base + lane*16 (HW rule)
__device__ __forceinline__ void gload_lds16(const u16* g, u16* l) {
    __builtin_amdgcn_global_load_lds(
        (const __attribute__((address_space(1))) void*)g,
        (__attribute__((address_space(3))) void*)l, 16, 0, 0);
}

// ---------------------------------------------------------------------------
// K0: fused preprocessing. Blocks [0,NSPLIT): split x into hi/lo bf16;
// [NSPLIT, NSPLIT+NCNT): csr_count; rest: W / Wo transpose+split.
#define NSPLIT 12500                 // NN*NF/8/256
#define NCNT   ((NE + 255) / 256)    // 3125
__global__ __launch_bounds__(256) void split_all(
        const float* __restrict__ x, u16* __restrict__ xhi, u16* __restrict__ xlo,
        const int* __restrict__ edge, int* __restrict__ cnt,
        const float* __restrict__ Wks, const float* __restrict__ Wo,
        u16* __restrict__ wthi, u16* __restrict__ wtlo,
        u16* __restrict__ wohi, u16* __restrict__ wolo) {
    if (blockIdx.x < NSPLIT) {
        size_t i = ((size_t)blockIdx.x * 256 + threadIdx.x) * 8;
        float4 v0 = *(const float4*)(x + i);
        float4 v1 = *(const float4*)(x + i + 4);
        float v[8] = {v0.x, v0.y, v0.z, v0.w, v1.x, v1.y, v1.z, v1.w};
        unsigned int hp[4], lp[4];
#pragma unroll
        for (int j = 0; j < 4; ++j) {
            u16 h0 = bf16_rne(v[2 * j]);
            u16 h1 = bf16_rne(v[2 * j + 1]);
            u16 l0 = bf16_rne(v[2 * j] - bf16_f(h0));
            u16 l1 = bf16_rne(v[2 * j + 1] - bf16_f(h1));
            hp[j] = (unsigned int)h0 | ((unsigned int)h1 << 16);
            lp[j] = (unsigned int)l0 | ((unsigned int)l1 << 16);
        }
        *(uint4*)(xhi + i) = make_uint4(hp[0], hp[1], hp[2], hp[3]);
        *(uint4*)(xlo + i) = make_uint4(lp[0], lp[1], lp[2], lp[3]);
    } else if (blockIdx.x < NSPLIT + NCNT) {
        int e = (blockIdx.x - NSPLIT) * 256 + threadIdx.x;
        if (e < NE) atomicAdd(&cnt[edge[e]], 1);
    } else {
        int b = blockIdx.x - NSPLIT - NCNT;   // 0..575
        if (b < 512) {
            int kf = b >> 7, n = b & 127;
            for (int f = threadIdx.x; f < NF; f += 256) {
                float v = Wks[(size_t)kf * (NF * NH) + (size_t)f * NH + n];
                u16 hb = bf16_rne(v);
                u16 lb = bf16_rne(v - bf16_f(hb));
                wthi[(size_t)b * NF + f] = hb;
                wtlo[(size_t)b * NF + f] = lb;
            }
        } else {
            int n = b - 512;   // 0..63
            for (int f = threadIdx.x; f < NF; f += 256) {
                float v = Wo[(size_t)f * NC + n];
                u16 hb = bf16_rne(v);
                u16 lb = bf16_rne(v - bf16_f(hb));
                wohi[(size_t)n * NF + f] = hb;
                wolo[(size_t)n * NF + f] = lb;
            }
        }
    }
}

// ---------------------------------------------------------------------------
// K1: h = x @ Wcat via 3-term split-bf16 MFMA, gload_lds staging, XCD-chunked
// bijective block swizzle.
__global__ __launch_bounds__(256) void gemm_h_mfma(
        const u16* __restrict__ xhi, const u16* __restrict__ xlo,
        const u16* __restrict__ wthi, const u16* __restrict__ wtlo,
        float* __restrict__ h) {
    __shared__ u16 Ah[128 * 32], Al[128 * 32], Bh[128 * 32], Bl[128 * 32];
    const int nwg = 4 * ((NN + 127) / 128);
    const int q = nwg / 8, r = nwg % 8;
    int o = blockIdx.x;
    int xcd = o & 7, pos = o >> 3;
    int wg = (xcd < r ? xcd * (q + 1) : r * (q + 1) + (xcd - r) * q) + pos;
    int m0 = (wg >> 2) * 128, n0 = (wg & 3) * 128;

    int tid = threadIdx.x;
    int lane = tid & 63;
    int wave = tid >> 6, wm = wave >> 1, wn = wave & 1;
    f32x4 acc[4][4];
#pragma unroll
    for (int i = 0; i < 4; ++i)
#pragma unroll
        for (int j = 0; j < 4; ++j) acc[i][j] = (f32x4)(0.f);

    u16* sbuf = (wave == 0) ? Ah : (wave == 1) ? Al : (wave == 2) ? Bh : Bl;
    const u16* gbase = (wave == 0) ? xhi : (wave == 1) ? xlo
                     : (wave == 2) ? wthi : wtlo;
    int rowbase = (wave < 2) ? m0 : n0;
    int c16s = (lane & 3) ^ ((lane >> 2) & 3) ^ (lane >> 4);
    const u16* gsrc[8];
#pragma unroll
    for (int i = 0; i < 8; ++i) {
        int rowg = rowbase + 16 * i + (lane >> 2);
        if (wave < 2 && rowg >= NN) rowg = NN - 1;
        gsrc[i] = gbase + (size_t)rowg * NF + c16s * 8;
    }

    const int arow = wm * 64 + (lane & 15);
    const int brow = wn * 64 + (lane & 15);
    const int rc16 = (lane >> 4) ^ ((lane & 3) ^ ((lane >> 2) & 3));
    const int fragoff = rc16 * 8;

    for (int k0 = 0; k0 < NF; k0 += 32) {
        __syncthreads();
#pragma unroll
        for (int i = 0; i < 8; ++i)
            gload_lds16(gsrc[i] + k0, sbuf + i * 512);
        __syncthreads();
        bf16x8 ah[4], al[4], bh[4], bl[4];
#pragma unroll
        for (int mi = 0; mi < 4; ++mi) {
            ah[mi] = *(const bf16x8*)(Ah + (arow + mi * 16) * 32 + fragoff);
            al[mi] = *(const bf16x8*)(Al + (arow + mi * 16) * 32 + fragoff);
        }
#pragma unroll
        for (int ni = 0; ni < 4; ++ni) {
            bh[ni] = *(const bf16x8*)(Bh + (brow + ni * 16) * 32 + fragoff);
            bl[ni] = *(const bf16x8*)(Bl + (brow + ni * 16) * 32 + fragoff);
        }
#pragma unroll
        for (int mi = 0; mi < 4; ++mi)
#pragma unroll
            for (int ni = 0; ni < 4; ++ni) {
                acc[mi][ni] = __builtin_amdgcn_mfma_f32_16x16x32_bf16(
                    ah[mi], bh[ni], acc[mi][ni], 0, 0, 0);
                acc[mi][ni] = __builtin_amdgcn_mfma_f32_16x16x32_bf16(
                    ah[mi], bl[ni], acc[mi][ni], 0, 0, 0);
                acc[mi][ni] = __builtin_amdgcn_mfma_f32_16x16x32_bf16(
                    al[mi], bh[ni], acc[mi][ni], 0, 0, 0);
            }
    }
#pragma unroll
    for (int mi = 0; mi < 4; ++mi) {
        int mbase = m0 + wm * 64 + mi * 16 + (lane >> 4) * 4;
#pragma unroll
        for (int ni = 0; ni < 4; ++ni) {
            int n = n0 + wn * 64 + ni * 16 + (lane & 15);
#pragma unroll
            for (int r2 = 0; r2 < 4; ++r2) {
                int m = mbase + r2;
                if (m < NN) h[(size_t)m * NF + n] = acc[mi][ni][r2];
            }
        }
    }
}

// ---------------------------------------------------------------------------
// K2: routing/attention scalars from h, packed per node. 2048 blocks so each
// SIMD carries ~8 waves (R12's 256-block version had 1 wave/SIMD -> latency-
// starved).
__global__ __launch_bounds__(256) void compute_svals_h(
        const float* __restrict__ h, const float* __restrict__ a_k,
        const float* __restrict__ a_att,
        float* __restrict__ sv1, float* __restrict__ sv2) {
    __shared__ float Ak[4][1024];
    __shared__ float Aa[4][256];
    for (int i = threadIdx.x; i < 4096; i += 256) Ak[i >> 10][i & 1023] = a_k[i];
    for (int i = threadIdx.x; i < 1024; i += 256) Aa[i >> 8][i & 255] = a_att[i];
    __syncthreads();
    int w = threadIdx.x >> 6, lane = threadIdx.x & 63;
    for (int n = blockIdx.x * 4 + w; n < NN; n += gridDim.x * 4) {
        const float* hr = h + (size_t)n * NF;
        float accS[4] = {0, 0, 0, 0}, accD[4] = {0, 0, 0, 0};
        float accQ1[4] = {0, 0, 0, 0}, accQ2[4] = {0, 0, 0, 0};
#pragma unroll
        for (int i = 0; i < 8; ++i) {
            int f = i * 64 + lane;
            float hv = hr[f];
#pragma unroll
            for (int k = 0; k < 4; ++k) {
                accS[k] = fmaf(hv, Ak[k][f], accS[k]);
                accD[k] = fmaf(hv, Ak[k][512 + f], accD[k]);
            }
            accQ1[i >> 1] = fmaf(hv, Aa[i >> 1][f & 127], accQ1[i >> 1]);
            accQ2[i >> 1] = fmaf(hv, Aa[i >> 1][128 + (f & 127)], accQ2[i >> 1]);
        }
#pragma unroll
        for (int off = 32; off >= 1; off >>= 1) {
#pragma unroll
            for (int k = 0; k < 4; ++k) {
                accS[k] += __shfl_xor(accS[k], off);
                accD[k] += __shfl_xor(accD[k], off);
                accQ1[k] += __shfl_xor(accQ1[k], off);
                accQ2[k] += __shfl_xor(accQ2[k], off);
            }
        }
        if (lane == 0) {
#pragma unroll
            for (int k = 0; k < 4; ++k) {
                sv1[(size_t)n * 8 + k]     = accS[k];
                sv1[(size_t)n * 8 + 4 + k] = accQ1[k];
                sv2[(size_t)n * 8 + k]     = accD[k];
                sv2[(size_t)n * 8 + 4 + k] = accQ2[k];
            }
        }
    }
}

// ---------------------------------------------------------------------------
__global__ __launch_bounds__(1024) void csr_scan(const int* __restrict__ cnt,
                                                 int* __restrict__ start) {
    __shared__ int part[1024];
    int t = threadIdx.x;
    const int CH = (NN + 1023) / 1024;  // 49
    int base = t * CH;
    int s = 0;
    for (int i = 0; i < CH; ++i) {
        int idx = base + i;
        if (idx < NN) s += cnt[idx];
    }
    part[t] = s;
    __syncthreads();
    for (int off = 1; off < 1024; off <<= 1) {
        int v = (t >= off) ? part[t - off] : 0;
        __syncthreads();
        part[t] += v;
        __syncthreads();
    }
    int run = (t == 0) ? 0 : part[t - 1];
    for (int i = 0; i < CH; ++i) {
        int idx = base + i;
        if (idx < NN) { start[idx] = run; run += cnt[idx]; }
    }
    if (t == 1023) start[NN] = run;
}

// ---------------------------------------------------------------------------
// K3: edge-parallel scalar precompute + CSR fill. One thread per edge.
__global__ __launch_bounds__(256) void edge_pre1(
        const int* __restrict__ edge, const int* __restrict__ start,
        int* __restrict__ cursor,
        const float* __restrict__ sv1, const float* __restrict__ sv2,
        int4* __restrict__ rec, double* __restrict__ att_acc) {
    __shared__ float blk[4];
    int tid = threadIdx.x;
    int e = blockIdx.x * 256 + tid;
    float t2 = 0.f;
    if (e < NE) {
        int src = edge[e];
        int dst = edge[NE + e];
        const float* p1 = sv1 + (size_t)src * 8;
        const float* p2 = sv2 + (size_t)dst * 8;
        float4 ss = *(const float4*)(p1);
        float4 q1 = *(const float4*)(p1 + 4);
        float4 sd = *(const float4*)(p2);
        float4 q2 = *(const float4*)(p2 + 4);
        float l0 = ss.x + sd.x, l1 = ss.y + sd.y, l2 = ss.z + sd.z, l3 = ss.w + sd.w;
        int i1 = 0; float v1 = l0;
        if (l1 > v1) { v1 = l1; i1 = 1; }
        if (l2 > v1) { v1 = l2; i1 = 2; }
        if (l3 > v1) { v1 = l3; i1 = 3; }
        int i2 = 0; float v2 = -3.4e38f;
        if (i1 != 0)            { v2 = l0; i2 = 0; }
        if (i1 != 1 && l1 > v2) { v2 = l1; i2 = 1; }
        if (i1 != 2 && l2 > v2) { v2 = l2; i2 = 2; }
        if (i1 != 3 && l3 > v2) { v2 = l3; i2 = 3; }
        float esum = expf(l0 - v1) + expf(l1 - v1) + expf(l2 - v1) + expf(l3 - v1);
        t2 = (1.f + expf(v2 - v1)) / esum;
        float q1v1 = i1 == 0 ? q1.x : i1 == 1 ? q1.y : i1 == 2 ? q1.z : q1.w;
        float q2v1 = i1 == 0 ? q2.x : i1 == 1 ? q2.y : i1 == 2 ? q2.z : q2.w;
        float q1v2 = i2 == 0 ? q1.x : i2 == 1 ? q1.y : i2 == 2 ? q1.z : q1.w;
        float q2v2 = i2 == 0 ? q2.x : i2 == 1 ? q2.y : i2 == 2 ? q2.z : q2.w;
        float sv1v = q1v1 + q2v1, sv2v = q1v2 + q2v2;
        float ee1 = expf(-(sv1v >= 0.f ? sv1v : LRELU_ALPHA * sv1v));
        float ee2 = expf(-(sv2v >= 0.f ? sv2v : LRELU_ALPHA * sv2v));
        int p = start[src] + atomicAdd(&cursor[src], 1);
        rec[p] = make_int4(dst, src | (i1 << 16) | (i2 << 18),
                           __float_as_int(ee1), __float_as_int(ee2));
    }
#pragma unroll
    for (int off = 32; off >= 1; off >>= 1) t2 += __shfl_xor(t2, off);
    if ((tid & 63) == 0) blk[tid >> 6] = t2;
    __syncthreads();
    if (tid == 0)
        atomicAdd(att_acc, (double)(blk[0] + blk[1] + blk[2] + blk[3]));
}

// ---------------------------------------------------------------------------
// K4: layer-1 gather, unrolled x4 (load-phase / accumulate-phase split so up
// to 4 rec + 16 row loads are in flight). Per-wave accumulation order is by
// increasing j, identical to the rolled loop -> bit-identical results.
#define G1_LOAD(RR, T)                                                          \
    int i1##T = __builtin_amdgcn_readfirstlane(((RR).y >> 16) & 3);             \
    int i2##T = __builtin_amdgcn_readfirstlane(((RR).y >> 18) & 3);             \
    int dd##T = __builtin_amdgcn_readfirstlane((RR).x);                         \
    float w1##T = __uint_as_float(__builtin_amdgcn_readfirstlane((RR).z));      \
    float w2##T = __uint_as_float(__builtin_amdgcn_readfirstlane((RR).w));      \
    const float* hr##T = h + (size_t)dd##T * NF + lane;                         \
    float v1a##T = hr##T[i1##T * 128];                                          \
    float v1b##T = hr##T[i1##T * 128 + 64];                                     \
    float v2a##T = hr##T[i2##T * 128];                                          \
    float v2b##T = hr##T[i2##T * 128 + 64];

#define G1_ACC(T)                                                               \
    switch (i1##T) {                                                            \
        case 0: a00 = fmaf(w1##T, v1a##T, a00); a01 = fmaf(w1##T, v1b##T, a01); rs0 += w1##T; break; \
        case 1: a10 = fmaf(w1##T, v1a##T, a10); a11 = fmaf(w1##T, v1b##T, a11); rs1 += w1##T; break; \
        case 2: a20 = fmaf(w1##T, v1a##T, a20); a21 = fmaf(w1##T, v1b##T, a21); rs2 += w1##T; break; \
        default:a30 = fmaf(w1##T, v1a##T, a30); a31 = fmaf(w1##T, v1b##T, a31); rs3 += w1##T; break; \
    }                                                                           \
    switch (i2##T) {                                                            \
        case 0: a00 = fmaf(w2##T, v2a##T, a00); a01 = fmaf(w2##T, v2b##T, a01); rs0 += w2##T; break; \
        case 1: a10 = fmaf(w2##T, v2a##T, a10); a11 = fmaf(w2##T, v2b##T, a11); rs1 += w2##T; break; \
        case 2: a20 = fmaf(w2##T, v2a##T, a20); a21 = fmaf(w2##T, v2b##T, a21); rs2 += w2##T; break; \
        default:a30 = fmaf(w2##T, v2a##T, a30); a31 = fmaf(w2##T, v2b##T, a31); rs3 += w2##T; break; \
    }

__global__ __launch_bounds__(256) void node_gather1(
        const int* __restrict__ start, const int4* __restrict__ rec,
        const float* __restrict__ h,
        u16* __restrict__ ahi, u16* __restrict__ alo) {
    __shared__ float red[4][512];
    __shared__ float rsred[4][4];
    int n = blockIdx.x;
    int w = threadIdx.x >> 6, lane = threadIdx.x & 63;
    int j0 = __builtin_amdgcn_readfirstlane(start[n]);
    int j1 = __builtin_amdgcn_readfirstlane(start[n + 1]);
    float a00 = 0.f, a01 = 0.f, a10 = 0.f, a11 = 0.f;
    float a20 = 0.f, a21 = 0.f, a30 = 0.f, a31 = 0.f;
    float rs0 = 0.f, rs1 = 0.f, rs2 = 0.f, rs3 = 0.f;
    int j = j0 + w;
    for (; j + 12 < j1; j += 16) {      // 4 records in flight
        int4 r0 = rec[j];
        int4 r1 = rec[j + 4];
        int4 r2 = rec[j + 8];
        int4 r3 = rec[j + 12];
        G1_LOAD(r0, A) G1_LOAD(r1, B) G1_LOAD(r2, C) G1_LOAD(r3, D)
        G1_ACC(A) G1_ACC(B) G1_ACC(C) G1_ACC(D)
    }
    for (; j < j1; j += 4) {
        int4 r0 = rec[j];
        G1_LOAD(r0, A)
        G1_ACC(A)
    }
    red[w][lane]       = a00; red[w][64 + lane]  = a01;
    red[w][128 + lane] = a10; red[w][192 + lane] = a11;
    red[w][256 + lane] = a20; red[w][320 + lane] = a21;
    red[w][384 + lane] = a30; red[w][448 + lane] = a31;
    if (lane == 0) {
        rsred[w][0] = rs0; rsred[w][1] = rs1; rsred[w][2] = rs2; rsred[w][3] = rs3;
    }
    __syncthreads();
    int t = threadIdx.x;
    float s0 = (red[0][t] + red[1][t]) + (red[2][t] + red[3][t]);
    float s1 = (red[0][256 + t] + red[1][256 + t]) + (red[2][256 + t] + red[3][256 + t]);
    int f0 = t >> 7, f1 = 2 + (t >> 7);
    float rsa = (rsred[0][f0] + rsred[1][f0]) + (rsred[2][f0] + rsred[3][f0]) + EPSF;
    float rsb = (rsred[0][f1] + rsred[1][f1]) + (rsred[2][f1] + rsred[3][f1]) + EPSF;
    float e0 = s0 / rsa; e0 = e0 > 0.f ? e0 : expm1f(e0);
    float e1 = s1 / rsb; e1 = e1 > 0.f ? e1 : expm1f(e1);
    u16 h0 = bf16_rne(e0), l0 = bf16_rne(e0 - bf16_f(h0));
    u16 h1 = bf16_rne(e1), l1 = bf16_rne(e1 - bf16_f(h1));
    u16* ah = ahi + (size_t)n * NF;
    u16* al = alo + (size_t)n * NF;
    ah[t] = h0; ah[256 + t] = h1;
    al[t] = l0; al[256 + t] = l1;
}

// ---------------------------------------------------------------------------
// K5: xo0 = elu_cat @ W_o via 3-term split-bf16 MFMA + fused s1o/s2o dots.
__global__ __launch_bounds__(256) void node_pass_mfma(
        const u16* __restrict__ ahi, const u16* __restrict__ alo,
        const u16* __restrict__ wohi, const u16* __restrict__ wolo,
        const float* __restrict__ a_out,
        float* __restrict__ xo0, float* __restrict__ s1o, float* __restrict__ s2o) {
    __shared__ u16 Ah[128 * 32], Al[128 * 32], Bh[64 * 32], Bl[64 * 32];
    __shared__ float part1[2][64][2];
    __shared__ float part2[2][64][2];
    int m0 = blockIdx.x * 128;
    int tid = threadIdx.x;
    int lane = tid & 63;
    int wave = tid >> 6, wm = wave >> 1, wn = wave & 1;
    f32x4 acc[4][2];
#pragma unroll
    for (int i = 0; i < 4; ++i)
#pragma unroll
        for (int j = 0; j < 2; ++j) acc[i][j] = (f32x4)(0.f);

    u16* sbuf = (wave == 0) ? Ah : (wave == 1) ? Al : (wave == 2) ? Bh : Bl;
    const u16* gbase = (wave == 0) ? ahi : (wave == 1) ? alo
                     : (wave == 2) ? wohi : wolo;
    int nld = (wave < 2) ? 8 : 4;
    int c16s = (lane & 3) ^ ((lane >> 2) & 3) ^ (lane >> 4);
    const u16* gsrc[8];
#pragma unroll
    for (int i = 0; i < 8; ++i) {
        int rowg = ((wave < 2) ? m0 : 0) + 16 * i + (lane >> 2);
        if (wave < 2 && rowg >= NN) rowg = NN - 1;
        gsrc[i] = gbase + (size_t)rowg * NF + c16s * 8;
    }

    const int arow = wm * 64 + (lane & 15);
    const int brow = wn * 32 + (lane & 15);
    const int rc16 = (lane >> 4) ^ ((lane & 3) ^ ((lane >> 2) & 3));
    const int fragoff = rc16 * 8;

    for (int k0 = 0; k0 < NF; k0 += 32) {
        __syncthreads();
        for (int i = 0; i < nld; ++i)
            gload_lds16(gsrc[i] + k0, sbuf + i * 512);
        __syncthreads();
        bf16x8 ah[4], al[4], bh[2], bl[2];
#pragma unroll
        for (int mi = 0; mi < 4; ++mi) {
            ah[mi] = *(const bf16x8*)(Ah + (arow + mi * 16) * 32 + fragoff);
            al[mi] = *(const bf16x8*)(Al + (arow + mi * 16) * 32 + fragoff);
        }
#pragma unroll
        for (int ni = 0; ni < 2; ++ni) {
            bh[ni] = *(const bf16x8*)(Bh + (brow + ni * 16) * 32 + fragoff);
            bl[ni] = *(const bf16x8*)(Bl + (brow + ni * 16) * 32 + fragoff);
        }
#pragma unroll
        for (int mi = 0; mi < 4; ++mi)
#pragma unroll
            for (int ni = 0; ni < 2; ++ni) {
                acc[mi][ni] = __builtin_amdgcn_mfma_f32_16x16x32_bf16(
                    ah[mi], bh[ni], acc[mi][ni], 0, 0, 0);
                acc[mi][ni] = __builtin_amdgcn_mfma_f32_16x16x32_bf16(
                    ah[mi], bl[ni], acc[mi][ni], 0, 0, 0);
                acc[mi][ni] = __builtin_amdgcn_mfma_f32_16x16x32_bf16(
                    al[mi], bh[ni], acc[mi][ni], 0, 0, 0);
            }
    }
    // xo0 store
#pragma unroll
    for (int mi = 0; mi < 4; ++mi) {
        int mbase = m0 + wm * 64 + mi * 16 + (lane >> 4) * 4;
#pragma unroll
        for (int ni = 0; ni < 2; ++ni) {
            int n = wn * 32 + ni * 16 + (lane & 15);
#pragma unroll
            for (int r2 = 0; r2 < 4; ++r2) {
                int m = mbase + r2;
                if (m < NN) xo0[(size_t)m * NC + n] = acc[mi][ni][r2];
            }
        }
    }
    // fused dots
    float ao1[2], ao2[2];
#pragma unroll
    for (int ni = 0; ni < 2; ++ni) {
        int c = wn * 32 + ni * 16 + (lane & 15);
        ao1[ni] = a_out[c];
        ao2[ni] = a_out[64 + c];
    }
#pragma unroll
    for (int mi = 0; mi < 4; ++mi)
#pragma unroll
        for (int r2 = 0; r2 < 4; ++r2) {
            float p1 = acc[mi][0][r2] * ao1[0] + acc[mi][1][r2] * ao1[1];
            float p2 = acc[mi][0][r2] * ao2[0] + acc[mi][1][r2] * ao2[1];
#pragma unroll
            for (int off = 8; off >= 1; off >>= 1) {
                p1 += __shfl_xor(p1, off);
                p2 += __shfl_xor(p2, off);
            }
            if ((lane & 15) == 0) {
                int rl = mi * 16 + (lane >> 4) * 4 + r2;
                part1[wm][rl][wn] = p1;
                part2[wm][rl][wn] = p2;
            }
        }
    __syncthreads();
    if (tid < 128) {
        int m = m0 + tid;
        if (m < NN) {
            s1o[m] = part1[tid >> 6][tid & 63][0] + part1[tid >> 6][tid & 63][1];
            s2o[m] = part2[tid >> 6][tid & 63][0] + part2[tid >> 6][tid & 63][1];
        }
    }
}

// ---------------------------------------------------------------------------
// K6: output attention gather, unrolled x4 (4 dependent chains in flight),
// fused elu + log-softmax; block 0 finalizes att_loss. Accumulation order per
// wave unchanged -> bit-identical.
__global__ __launch_bounds__(256) void node_gather2(
        const int* __restrict__ start, const int4* __restrict__ rec,
        const float* __restrict__ s1o, const float* __restrict__ s2o,
        const float* __restrict__ xo0, const double* __restrict__ att_acc,
        float* __restrict__ out) {
    __shared__ float red[4][64];
    __shared__ float rsl[4];
    if (blockIdx.x == 0 && threadIdx.x == 0)
        out[(size_t)NN * NC] = 1.f - (float)(att_acc[0] / (double)NE);
    int n = blockIdx.x;
    int w = threadIdx.x >> 6, lane = threadIdx.x & 63;
    int j0 = __builtin_amdgcn_readfirstlane(start[n]);
    int j1 = __builtin_amdgcn_readfirstlane(start[n + 1]);
    float s1n = s1o[n];
    float acc = 0.f, rsum = 0.f;
    int j = j0 + w;
    for (; j + 12 < j1; j += 16) {
        int d0 = __builtin_amdgcn_readfirstlane(rec[j].x);
        int d1 = __builtin_amdgcn_readfirstlane(rec[j + 4].x);
        int d2 = __builtin_amdgcn_readfirstlane(rec[j + 8].x);
        int d3 = __builtin_amdgcn_readfirstlane(rec[j + 12].x);
        float t0 = s1n + s2o[d0];
        float t1 = s1n + s2o[d1];
        float t2 = s1n + s2o[d2];
        float t3 = s1n + s2o[d3];
        float x0 = xo0[(size_t)d0 * NC + lane];
        float x1 = xo0[(size_t)d1 * NC + lane];
        float x2 = xo0[(size_t)d2 * NC + lane];
        float x3 = xo0[(size_t)d3 * NC + lane];
        float e0 = expf(-(t0 >= 0.f ? t0 : LRELU_ALPHA * t0));
        float e1 = expf(-(t1 >= 0.f ? t1 : LRELU_ALPHA * t1));
        float e2 = expf(-(t2 >= 0.f ? t2 : LRELU_ALPHA * t2));
        float e3 = expf(-(t3 >= 0.f ? t3 : LRELU_ALPHA * t3));
        acc = fmaf(e0, x0, acc); rsum += e0;
        acc = fmaf(e1, x1, acc); rsum += e1;
        acc = fmaf(e2, x2, acc); rsum += e2;
        acc = fmaf(e3, x3, acc); rsum += e3;
    }
    for (; j < j1; j += 4) {
        int d = __builtin_amdgcn_readfirstlane(rec[j].x);
        float sv = s1n + s2o[d];
        float e = expf(-(sv >= 0.f ? sv : LRELU_ALPHA * sv));
        acc = fmaf(e, xo0[(size_t)d * NC + lane], acc);
        rsum += e;
    }
    red[w][lane] = acc;
    if (lane == 0) rsl[w] = rsum;
    __syncthreads();
    if (w == 0) {
        float a = (red[0][lane] + red[1][lane]) + (red[2][lane] + red[3][lane]);
        float r = (rsl[0] + rsl[1]) + (rsl[2] + rsl[3]);
        float t = a / (r + EPSF);
        float v = t > 0.f ? t : expm1f(t);
        float m = v;
#pragma unroll
        for (int off = 32; off >= 1; off >>= 1) m = fmaxf(m, __shfl_xor(m, off));
        float p = expf(v - m);
#pragma unroll
        for (int off = 32; off >= 1; off >>= 1) p += __shfl_xor(p, off);
        out[(size_t)n * NC + lane] = v - m - logf(p);
    }
}

// ---------------------------------------------------------------------------
extern "C" void kernel_launch(void* const* d_in, const int* in_sizes, int n_in,
                              void* d_out, int out_size, void* d_ws, size_t ws_size,
                              hipStream_t stream) {
    const float* x     = (const float*)d_in[0];
    const int*   edge  = (const int*)d_in[1];
    const float* Wks   = (const float*)d_in[2];
    const float* a_k   = (const float*)d_in[3];
    const float* Wo    = (const float*)d_in[4];
    const float* a_att = (const float*)d_in[5];
    const float* a_out = (const float*)d_in[6];
    float* out = (float*)d_out;

    float* wsf = (float*)d_ws;
    float* h      = wsf + OFF_H;
    int4*  rec    = (int4*)(wsf + OFF_REC);
    float* xo0    = wsf + OFF_XO0;
    float* sv1    = wsf + OFF_SV1;
    float* sv2    = wsf + OFF_SV2;
    float* s1o    = wsf + OFF_S1O;
    float* s2o    = wsf + OFF_S2O;
    int*   startp = (int*)(wsf + OFF_START);
    int*   cnt    = (int*)(wsf + OFF_CNT);
    int*   cursor = (int*)(wsf + OFF_CURSOR);
    double* att   = (double*)(wsf + OFF_ATT);

    u16* xhi  = (u16*)(wsf + OFF_HP);
    u16* xlo  = xhi + (size_t)NN * NF;
    u16* ahi  = xhi;
    u16* alo  = xlo;
    u16* wthi = (u16*)(wsf + OFF_REC);
    u16* wtlo = wthi + (size_t)KF * NH * NF;
    u16* wohi = (u16*)(wsf + OFF_WOT);
    u16* wolo = wohi + (size_t)NC * NF;

    size_t zero_bytes = (size_t)(WS_FLOATS - OFF_CNT) * sizeof(float);
    hipMemsetAsync((char*)d_ws + (size_t)OFF_CNT * sizeof(float), 0, zero_bytes, stream);

    split_all<<<NSPLIT + NCNT + 576, 256, 0, stream>>>(
        x, xhi, xlo, edge, cnt, Wks, Wo, wthi, wtlo, wohi, wolo);
    csr_scan<<<1, 1024, 0, stream>>>(cnt, startp);
    gemm_h_mfma<<<4 * ((NN + 127) / 128), 256, 0, stream>>>(xhi, xlo, wthi, wtlo, h);
    compute_svals_h<<<2048, 256, 0, stream>>>(h, a_k, a_att, sv1, sv2);
    edge_pre1<<<(NE + 255) / 256, 256, 0, stream>>>(edge, startp, cursor,
                                                    sv1, sv2, rec, att);
    node_gather1<<<NN, 256, 0, stream>>>(startp, rec, h, ahi, alo);
    node_pass_mfma<<<(NN + 127) / 128, 256, 0, stream>>>(ahi, alo, wohi, wolo,
                                                         a_out, xo0, s1o, s2o);
    node_gather2<<<NN, 256, 0, stream>>>(startp, rec, s1o, s2o, xo0, att, out);
}